// Round 2
// baseline (202.741 us; speedup 1.0000x reference)
//
#include <hip/hip_runtime.h>
#include <math.h>

#define NPOS  2048
#define NANCH 4096          // pos + neg
#define CIN   1280
#define HID   128
#define W_    28
#define HW_   784           // 28*28
#define AHW   7056          // 9*784
#define FB    (CIN*HW_)     // floats per batch image
#define KSEL  8             // K-splits
#define KCH   160           // channels per K-split block
#define SUB   16            // channels per LDS slab
#define NSUB  (KCH/SUB)     // 10
#define CAP   4096          // per-image anchor list capacity (worst case)

__device__ __forceinline__ float sigmoidf_(float x) {
    return 1.0f / (1.0f + __expf(-x));
}

// ---------------------------------------------------------------------------
// K0a: zero per-image counters
// ---------------------------------------------------------------------------
__global__ void k_zero(int* __restrict__ cnt) {
    if (threadIdx.x < 64) cnt[threadIdx.x] = 0;
}

// ---------------------------------------------------------------------------
// K0b: bucket anchors by image. Slot order is nondeterministic but each
// anchor's arithmetic is slot-independent -> output bitwise deterministic.
// pack = (g << 10) | hw   (g < 4096 fits 12b, hw < 784 fits 10b)
// ---------------------------------------------------------------------------
__global__ void k_bucket(const int* __restrict__ posi, const int* __restrict__ negi,
                         int* __restrict__ cnt, int* __restrict__ list) {
    const int g = blockIdx.x * 256 + threadIdx.x;
    if (g >= NANCH) return;
    const int aidx = (g < NPOS) ? posi[g] : negi[g - NPOS];
    const int b    = aidx / AHW;
    const int hw   = (aidx - b * AHW) % HW_;
    const int slot = atomicAdd(&cnt[b], 1);
    list[b * CAP + slot] = (g << 10) | hw;
}

// ---------------------------------------------------------------------------
// K0c: transpose W1[o][k] -> W1T[k][o] so GEMM weight reads are coalesced.
// ---------------------------------------------------------------------------
__global__ void k_transpose(const float* __restrict__ W1, float* __restrict__ W1T) {
    const int id = blockIdx.x * 256 + threadIdx.x;   // over 1280*128
    if (id >= CIN * HID) return;
    const int o = id / CIN;
    const int k = id - o * CIN;
    W1T[(size_t)k * HID + o] = W1[id];
}

// ---------------------------------------------------------------------------
// K1: streaming GEMM1. grid = (64 images, KSEL k-chunks, 2 half-tiles).
// Streams 16-channel plane slabs (coalesced) into LDS, gathers this image's
// anchors from LDS, FMAs vs W1T (L2-hot). Writes Hp[ks][g][o] partials.
// ---------------------------------------------------------------------------
__global__ __launch_bounds__(256) void k_gemm1(
    const float* __restrict__ F, const float* __restrict__ W1T,
    const int* __restrict__ cnt, const int* __restrict__ list,
    float* __restrict__ Hp)
{
    __shared__ float Pl[SUB * HW_];     // 50176 B plane slab
    __shared__ float Gl[2][SUB][64];    // 8192 B gathered columns
    __shared__ int   hwl[128];
    __shared__ int   gll[128];

    const int b  = blockIdx.x;
    const int ks = blockIdx.y;
    const int z  = blockIdx.z;
    const int t  = threadIdx.x;
    const int nb = cnt[b];
    const int kbase = ks * KCH;

    const int tx = t & 15;     // 4 anchors each
    const int ty = t >> 4;     // 8 outputs each
    const int p  = t & 63;
    const int kq = t >> 6;     // 0..3

    for (int abase = z * 128; abase < nb; abase += 256) {
        __syncthreads();       // protect hwl/gll from previous pass readers
        if (t < 128) {
            const int s = abase + t;
            if (s < nb) {
                const int pk = list[b * CAP + s];
                hwl[t] = pk & 1023;
                gll[t] = pk >> 10;
            } else {
                hwl[t] = 0;
                gll[t] = -1;
            }
        }

        float acc[2][4][8];
#pragma unroll
        for (int tt = 0; tt < 2; ++tt)
#pragma unroll
            for (int i = 0; i < 4; ++i)
#pragma unroll
                for (int j = 0; j < 8; ++j) acc[tt][i][j] = 0.0f;

        for (int sub = 0; sub < NSUB; ++sub) {
            const int kb = kbase + sub * SUB;
            __syncthreads();   // prev compute done (Gl), prev build done (Pl)
            // stage plane slab: contiguous 50 KB, fully coalesced float4
            {
                const float4* src = (const float4*)(F + (size_t)b * FB + (size_t)kb * HW_);
                float4* Pl4 = (float4*)Pl;
                for (int i = t; i < SUB * HW_ / 4; i += 256) Pl4[i] = src[i];
            }
            __syncthreads();   // Pl ready
            // gather anchor columns into compact Gl
#pragma unroll
            for (int tt = 0; tt < 2; ++tt)
#pragma unroll
                for (int pass = 0; pass < 4; ++pass) {
                    const int kk = pass * 4 + kq;
                    Gl[tt][kk][p] = Pl[kk * HW_ + hwl[tt * 64 + p]];
                }
            __syncthreads();   // Gl ready
            // FMA: 4 anchors x 8 outs x 2 half-tiles per thread
#pragma unroll
            for (int kk = 0; kk < SUB; ++kk) {
                const float4 wA = *(const float4*)&W1T[(size_t)(kb + kk) * HID + ty * 8];
                const float4 wB = *(const float4*)&W1T[(size_t)(kb + kk) * HID + ty * 8 + 4];
                const float wv[8] = {wA.x, wA.y, wA.z, wA.w, wB.x, wB.y, wB.z, wB.w};
#pragma unroll
                for (int tt = 0; tt < 2; ++tt) {
                    const float4 g4 = *(const float4*)&Gl[tt][kk][tx * 4];
                    const float gg[4] = {g4.x, g4.y, g4.z, g4.w};
#pragma unroll
                    for (int i = 0; i < 4; ++i)
#pragma unroll
                        for (int j = 0; j < 8; ++j)
                            acc[tt][i][j] = fmaf(gg[i], wv[j], acc[tt][i][j]);
                }
            }
        }

        __syncthreads();       // gll stable until here; also compute finished
#pragma unroll
        for (int tt = 0; tt < 2; ++tt)
#pragma unroll
            for (int i = 0; i < 4; ++i) {
                const int g = gll[tt * 64 + tx * 4 + i];
                if (g >= 0) {
                    float* dst = Hp + ((size_t)ks * NANCH + g) * HID + ty * 8;
                    float4 s0 = {acc[tt][i][0], acc[tt][i][1], acc[tt][i][2], acc[tt][i][3]};
                    float4 s1 = {acc[tt][i][4], acc[tt][i][5], acc[tt][i][6], acc[tt][i][7]};
                    *(float4*)dst       = s0;
                    *(float4*)(dst + 4) = s1;
                }
            }
    }
}

// ---------------------------------------------------------------------------
// K2: reduce KSEL partials + bias + leaky_relu -> H[4096][128]
// ---------------------------------------------------------------------------
__global__ __launch_bounds__(256) void k_reduce_bias(
    const float* __restrict__ Hp, const float* __restrict__ b1,
    float* __restrict__ Hout)
{
    const int j = blockIdx.x * 256 + threadIdx.x;   // < NANCH*HID
    const int o = j & (HID - 1);
    float s = b1[o];
#pragma unroll
    for (int ks = 0; ks < KSEL; ++ks) s += Hp[(size_t)ks * (NANCH * HID) + j];
    Hout[j] = (s > 0.0f) ? s : 0.01f * s;
}

// ---------------------------------------------------------------------------
// K3: wave-per-anchor: layer-2 (25 or 1 rows) + IoU/argmax + losses
// ---------------------------------------------------------------------------
__global__ __launch_bounds__(256) void k_loss(
    const float* __restrict__ H, const float* __restrict__ W2,
    const float* __restrict__ b2, const int* __restrict__ posi,
    const int* __restrict__ negi, const float* __restrict__ bboxes,
    const float* __restrict__ anc, float* __restrict__ contrib)
{
    const int wid  = threadIdx.x >> 6;
    const int lane = threadIdx.x & 63;
    const int g    = blockIdx.x * 4 + wid;

    const int aidx = (g < NPOS) ? posi[g] : negi[g - NPOS];
    const int b   = aidx / AHW;
    const int rem = aidx - b * AHW;
    const int a   = rem / HW_;
    const int hw  = rem - a * HW_;
    const int hh  = hw / W_;
    const int ww  = hw - hh * W_;

    const float2 h2 = *(const float2*)&H[(size_t)g * HID + 2 * lane];

    if (g < NPOS) {
        float out[25];
#pragma unroll
        for (int j = 0; j < 25; ++j) {
            const int row = (j < 5) ? (5 * a + j) : (40 + j);
            const float2 w = *(const float2*)&W2[(size_t)row * HID + 2 * lane];
            float v = fmaf(w.x, h2.x, w.y * h2.y);
#pragma unroll
            for (int off = 1; off < 64; off <<= 1) v += __shfl_xor(v, off, 64);
            out[j] = v + b2[row];
        }

        const float wa = anc[2 * a], ha = anc[2 * a + 1];
        const float cx = ww + 0.5f, cy = hh + 0.5f;
        const float ax1 = cx - 0.5f * wa, ay1 = cy - 0.5f * ha;
        const float ax2 = cx + 0.5f * wa, ay2 = cy + 0.5f * ha;
        const float areap = wa * ha;

        float v; int vi = lane;
        if (lane < 40) {
            const float* bb = &bboxes[(size_t)(b * 40 + lane) * 5];
            const float bx1 = bb[0], by1 = bb[1], bx2 = bb[2], by2 = bb[3];
            const float areab = (bx2 - bx1) * (by2 - by1);
            const float ix1 = fmaxf(ax1, bx1), iy1 = fmaxf(ay1, by1);
            const float ix2 = fminf(ax2, bx2), iy2 = fminf(ay2, by2);
            const float inter = fmaxf(ix2 - ix1, 0.0f) * fmaxf(iy2 - iy1, 0.0f);
            v = inter / (areap + areab - inter);
        } else {
            v = -1.0f;
        }
#pragma unroll
        for (int off = 1; off < 64; off <<= 1) {
            const float ov = __shfl_xor(v, off, 64);
            const int   oi = __shfl_xor(vi, off, 64);
            if (ov > v || (ov == v && oi < vi)) { v = ov; vi = oi; }
        }
        const int m = vi;

        const float* gt = &bboxes[(size_t)(b * 40 + m) * 5];
        const float gx1 = gt[0], gy1 = gt[1], gx2 = gt[2], gy2 = gt[3];
        const int   gcls = (int)gt[4];
        const float xb = 0.5f * (gx1 + gx2), yb = 0.5f * (gy1 + gy2);
        const float wb = gx2 - gx1, hb = gy2 - gy1;
        const float go0 = xb - cx, go1 = yb - cy;
        const float go2 = __logf(wb / wa), go3 = __logf(hb / ha);

        const float o0 = sigmoidf_(out[1]) - 0.5f;
        const float o1 = sigmoidf_(out[2]) - 0.5f;
        const float o2 = out[3], o3 = out[4];
        const float reg = (o0 - go0) * (o0 - go0) + (o1 - go1) * (o1 - go1) +
                          (o2 - go2) * (o2 - go2) + (o3 - go3) * (o3 - go3);

        const float conf = sigmoidf_(out[0]);
        const float conft = (conf - 1.0f) * (conf - 1.0f);

        float mx = out[5];
#pragma unroll
        for (int c = 1; c < 20; ++c) mx = fmaxf(mx, out[5 + c]);
        float se = 0.0f;
#pragma unroll
        for (int c = 0; c < 20; ++c) se += __expf(out[5 + c] - mx);
        float lgt = 0.0f;
#pragma unroll
        for (int c = 0; c < 20; ++c) if (c == gcls) lgt = out[5 + c];
        const float clst = -(lgt - mx - __logf(se));

        if (lane == 0)
            contrib[g] = conft * (1.0f / 4096.0f) + reg * (1.0f / 2048.0f) +
                         clst * (1.0f / 2048.0f);
    } else {
        const int row = 5 * a;
        const float2 w = *(const float2*)&W2[(size_t)row * HID + 2 * lane];
        float v = fmaf(w.x, h2.x, w.y * h2.y);
#pragma unroll
        for (int off = 1; off < 64; off <<= 1) v += __shfl_xor(v, off, 64);
        const float conf = sigmoidf_(v + b2[row]);
        if (lane == 0) contrib[g] = conf * conf * (1.0f / 4096.0f);
    }
}

// ---------------------------------------------------------------------------
// K4: final reduction
// ---------------------------------------------------------------------------
__global__ __launch_bounds__(256) void k_final(const float* __restrict__ contrib,
                                               float* __restrict__ out)
{
    __shared__ float red[256];
    const int t = threadIdx.x;
    float s = 0.0f;
    for (int i = t; i < NANCH; i += 256) s += contrib[i];
    red[t] = s;
    __syncthreads();
    for (int st = 128; st > 0; st >>= 1) {
        if (t < st) red[t] += red[t + st];
        __syncthreads();
    }
    if (t == 0) out[0] = red[0];
}

extern "C" void kernel_launch(void* const* d_in, const int* in_sizes, int n_in,
                              void* d_out, int out_size, void* d_ws, size_t ws_size,
                              hipStream_t stream)
{
    const float* F      = (const float*)d_in[0];
    const float* bboxes = (const float*)d_in[1];
    const int*   posi   = (const int*)d_in[2];
    const int*   negi   = (const int*)d_in[3];
    const float* W1     = (const float*)d_in[4];
    const float* b1     = (const float*)d_in[5];
    const float* W2     = (const float*)d_in[6];
    const float* b2     = (const float*)d_in[7];
    const float* anc    = (const float*)d_in[8];
    float* out = (float*)d_out;

    // workspace layout (all offsets 16B-aligned)
    int*   cnt     = (int*)d_ws;                       // 64
    int*   list    = cnt + 64;                         // 64*4096
    float* W1T     = (float*)(list + 64 * CAP);        // 1280*128
    float* Hp      = W1T + (size_t)CIN * HID;          // KSEL*4096*128
    float* Hbuf    = Hp + (size_t)KSEL * NANCH * HID;  // 4096*128
    float* contrib = Hbuf + (size_t)NANCH * HID;       // 4096

    k_zero<<<1, 64, 0, stream>>>(cnt);
    k_bucket<<<NANCH / 256, 256, 0, stream>>>(posi, negi, cnt, list);
    k_transpose<<<(CIN * HID + 255) / 256, 256, 0, stream>>>(W1, W1T);
    k_gemm1<<<dim3(64, KSEL, 2), 256, 0, stream>>>(F, W1T, cnt, list, Hp);
    k_reduce_bias<<<(NANCH * HID) / 256, 256, 0, stream>>>(Hp, b1, Hbuf);
    k_loss<<<NANCH / 4, 256, 0, stream>>>(Hbuf, W2, b2, posi, negi, bboxes, anc,
                                          contrib);
    k_final<<<1, 256, 0, stream>>>(contrib, out);
    (void)in_sizes; (void)n_in; (void)out_size; (void)ws_size;
}

// Round 3
// 115.235 us; speedup vs baseline: 1.7594x; 1.7594x over previous
//
#include <hip/hip_runtime.h>
#include <math.h>

#define NPOS   2048
#define NANCH  4096          // pos + neg
#define CIN    1280
#define HID    128
#define W_     28
#define HW_    784           // 28*28
#define AHW    7056          // 9*784
#define FB     (CIN*HW_)     // floats per batch image
#define CAP    4096          // per-image anchor list capacity
#define GSLAB  8             // channels per gather slab
#define NGSLAB (CIN/GSLAB)   // 160

__device__ __forceinline__ float sigmoidf_(float x) {
    return 1.0f / (1.0f + __expf(-x));
}
__device__ __forceinline__ unsigned short f2bf(float x) {   // RNE f32->bf16
    unsigned int u = __float_as_uint(x);
    return (unsigned short)((u + 0x7fffu + ((u >> 16) & 1u)) >> 16);
}
__device__ __forceinline__ float bf_lo(unsigned int w) { return __uint_as_float(w << 16); }
__device__ __forceinline__ float bf_hi(unsigned int w) { return __uint_as_float(w & 0xffff0000u); }

// ---------------------------------------------------------------------------
// K0a: zero per-image counters
// ---------------------------------------------------------------------------
__global__ void k_zero(int* __restrict__ cnt) {
    if (threadIdx.x < 64) cnt[threadIdx.x] = 0;
}

// ---------------------------------------------------------------------------
// K0b: bucket anchors by image. Slot order nondeterministic, values written
// per-anchor are slot-independent -> bitwise-deterministic pipeline output.
// pack = (g << 10) | hw
// ---------------------------------------------------------------------------
__global__ void k_bucket(const int* __restrict__ posi, const int* __restrict__ negi,
                         int* __restrict__ cnt, int* __restrict__ list) {
    const int g = blockIdx.x * 256 + threadIdx.x;
    if (g >= NANCH) return;
    const int aidx = (g < NPOS) ? posi[g] : negi[g - NPOS];
    const int b    = aidx / AHW;
    const int hw   = (aidx - b * AHW) % HW_;
    const int slot = atomicAdd(&cnt[b], 1);
    list[b * CAP + slot] = (g << 10) | hw;
}

// ---------------------------------------------------------------------------
// K0c: transpose W1[o][k] -> W1T[k][o] (fp32, coalesced GEMM weight reads)
// ---------------------------------------------------------------------------
__global__ void k_transpose(const float* __restrict__ W1, float* __restrict__ W1T) {
    const int id = blockIdx.x * 256 + threadIdx.x;   // over 128*1280
    if (id >= CIN * HID) return;
    const int o = id / CIN;
    const int k = id - o * CIN;
    W1T[(size_t)k * HID + o] = W1[id];
}

// ---------------------------------------------------------------------------
// K1a: streaming gather. grid = (160 slabs, 64 images), 256 thr, 25 KB LDS.
// Stream 8-channel plane slab coalesced -> LDS; scatter this image's anchors
// into compact G[g][k] (bf16). One barrier per block, 6 blocks/CU resident.
// ---------------------------------------------------------------------------
__global__ __launch_bounds__(256) void k_gather(
    const float* __restrict__ F, const int* __restrict__ cnt,
    const int* __restrict__ list, unsigned short* __restrict__ G)
{
    __shared__ float Pl[GSLAB * HW_];   // 25088 B
    const int slab = blockIdx.x;
    const int b    = blockIdx.y;
    const int t    = threadIdx.x;
    const int kb   = slab * GSLAB;

    const float4* src = (const float4*)(F + (size_t)b * FB + (size_t)kb * HW_);
    float4* P4 = (float4*)Pl;
    for (int i = t; i < (GSLAB * HW_) / 4; i += 256) P4[i] = src[i];
    __syncthreads();

    const int nb = cnt[b];
    const int h  = t & 1;               // which 4-channel half
    for (int s0 = 0; s0 < nb; s0 += 128) {
        const int idx = s0 + (t >> 1);
        if (idx < nb) {
            const int pk = list[b * CAP + idx];
            const int hw = pk & 1023;
            const int g  = pk >> 10;
            const float v0 = Pl[(4 * h + 0) * HW_ + hw];
            const float v1 = Pl[(4 * h + 1) * HW_ + hw];
            const float v2 = Pl[(4 * h + 2) * HW_ + hw];
            const float v3 = Pl[(4 * h + 3) * HW_ + hw];
            ushort4 o4;
            o4.x = f2bf(v0); o4.y = f2bf(v1); o4.z = f2bf(v2); o4.w = f2bf(v3);
            *(ushort4*)&G[(size_t)g * CIN + kb + 4 * h] = o4;
        }
    }
}

// ---------------------------------------------------------------------------
// K1b: dense GEMM  Hp[ks][g][o] (bf16 partials) = G[g][kchunk] * W1T
// grid = (64 anchor-tiles, KSEL). 64 anchors x 128 outs per block.
// LDS staged fp32 (converted once), inner loop pure fmaf + ds_read_b128.
// ---------------------------------------------------------------------------
__global__ __launch_bounds__(256) void k_gemm2(
    const unsigned short* __restrict__ G, const float* __restrict__ W1T,
    unsigned short* __restrict__ Hp, int kchunk)
{
    __shared__ float Gs[16][68];     // [kk][anchor]
    __shared__ float Wl[16][132];    // [kk][o]

    const int mt = blockIdx.x;
    const int ks = blockIdx.y;
    const int t  = threadIdx.x;
    const int g0 = mt * 64;
    const int kbase = ks * kchunk;
    const int tx = t & 15;           // 4 anchors each
    const int ty = t >> 4;           // 8 outputs each
    const int a  = t & 63;
    const int hh = (t >> 6) & 1;

    float acc[4][8];
#pragma unroll
    for (int i = 0; i < 4; ++i)
#pragma unroll
        for (int j = 0; j < 8; ++j) acc[i][j] = 0.0f;

    const int nsub = kchunk >> 4;
    for (int sub = 0; sub < nsub; ++sub) {
        const int kb = kbase + (sub << 4);
        __syncthreads();
        // stage G slab: 64 anchors x 16 ch bf16 -> fp32 Gs[kk][a]
        if (t < 128) {
            const uint4 raw = *(const uint4*)&G[(size_t)(g0 + a) * CIN + kb + 8 * hh];
            const int k8 = 8 * hh;
            Gs[k8 + 0][a] = bf_lo(raw.x); Gs[k8 + 1][a] = bf_hi(raw.x);
            Gs[k8 + 2][a] = bf_lo(raw.y); Gs[k8 + 3][a] = bf_hi(raw.y);
            Gs[k8 + 4][a] = bf_lo(raw.z); Gs[k8 + 5][a] = bf_hi(raw.z);
            Gs[k8 + 6][a] = bf_lo(raw.w); Gs[k8 + 7][a] = bf_hi(raw.w);
        }
        // stage W slab: 16 x 128 fp32
#pragma unroll
        for (int r = 0; r < 2; ++r) {
            const int idx = t + 256 * r;
            const int kk  = idx >> 5;
            const int c4  = idx & 31;
            const float4 wv = *(const float4*)&W1T[(size_t)(kb + kk) * HID + 4 * c4];
            *(float4*)&Wl[kk][4 * c4] = wv;
        }
        __syncthreads();
#pragma unroll
        for (int kk = 0; kk < 16; ++kk) {
            const float4 g4 = *(const float4*)&Gs[kk][tx << 2];
            const float4 wA = *(const float4*)&Wl[kk][ty << 3];
            const float4 wB = *(const float4*)&Wl[kk][(ty << 3) + 4];
            const float gg[4] = {g4.x, g4.y, g4.z, g4.w};
            const float wv[8] = {wA.x, wA.y, wA.z, wA.w, wB.x, wB.y, wB.z, wB.w};
#pragma unroll
            for (int i = 0; i < 4; ++i)
#pragma unroll
                for (int j = 0; j < 8; ++j)
                    acc[i][j] = fmaf(gg[i], wv[j], acc[i][j]);
        }
    }

#pragma unroll
    for (int i = 0; i < 4; ++i) {
        uint4 pk;
        pk.x = (unsigned)f2bf(acc[i][0]) | ((unsigned)f2bf(acc[i][1]) << 16);
        pk.y = (unsigned)f2bf(acc[i][2]) | ((unsigned)f2bf(acc[i][3]) << 16);
        pk.z = (unsigned)f2bf(acc[i][4]) | ((unsigned)f2bf(acc[i][5]) << 16);
        pk.w = (unsigned)f2bf(acc[i][6]) | ((unsigned)f2bf(acc[i][7]) << 16);
        *(uint4*)&Hp[((size_t)ks * NANCH + g0 + (tx << 2) + i) * HID + (ty << 3)] = pk;
    }
}

// ---------------------------------------------------------------------------
// K2: reduce KSEL bf16 partials + bias + leaky_relu -> Hbuf[4096][128] fp32
// ---------------------------------------------------------------------------
__global__ __launch_bounds__(256) void k_reduce_bias(
    const unsigned short* __restrict__ Hp, const float* __restrict__ b1,
    float* __restrict__ Hout, int ksel)
{
    const int tid  = blockIdx.x * 256 + threadIdx.x;   // over 65536 groups of 8
    const int base = tid * 8;
    const int o    = base & (HID - 1);
    float s[8];
    {
        const float4 bA = *(const float4*)&b1[o];
        const float4 bB = *(const float4*)&b1[o + 4];
        s[0] = bA.x; s[1] = bA.y; s[2] = bA.z; s[3] = bA.w;
        s[4] = bB.x; s[5] = bB.y; s[6] = bB.z; s[7] = bB.w;
    }
    for (int ks = 0; ks < ksel; ++ks) {
        const uint4 raw = *(const uint4*)&Hp[(size_t)ks * NANCH * HID + base];
        s[0] += bf_lo(raw.x); s[1] += bf_hi(raw.x);
        s[2] += bf_lo(raw.y); s[3] += bf_hi(raw.y);
        s[4] += bf_lo(raw.z); s[5] += bf_hi(raw.z);
        s[6] += bf_lo(raw.w); s[7] += bf_hi(raw.w);
    }
    float4 oA, oB;
    oA.x = (s[0] > 0.0f) ? s[0] : 0.01f * s[0];
    oA.y = (s[1] > 0.0f) ? s[1] : 0.01f * s[1];
    oA.z = (s[2] > 0.0f) ? s[2] : 0.01f * s[2];
    oA.w = (s[3] > 0.0f) ? s[3] : 0.01f * s[3];
    oB.x = (s[4] > 0.0f) ? s[4] : 0.01f * s[4];
    oB.y = (s[5] > 0.0f) ? s[5] : 0.01f * s[5];
    oB.z = (s[6] > 0.0f) ? s[6] : 0.01f * s[6];
    oB.w = (s[7] > 0.0f) ? s[7] : 0.01f * s[7];
    *(float4*)&Hout[base]     = oA;
    *(float4*)&Hout[base + 4] = oB;
}

// ---------------------------------------------------------------------------
// K3: wave-per-anchor: layer-2 (25 or 1 rows) + IoU/argmax + losses
// ---------------------------------------------------------------------------
__global__ __launch_bounds__(256) void k_loss(
    const float* __restrict__ H, const float* __restrict__ W2,
    const float* __restrict__ b2, const int* __restrict__ posi,
    const int* __restrict__ negi, const float* __restrict__ bboxes,
    const float* __restrict__ anc, float* __restrict__ contrib)
{
    const int wid  = threadIdx.x >> 6;
    const int lane = threadIdx.x & 63;
    const int g    = blockIdx.x * 4 + wid;

    const int aidx = (g < NPOS) ? posi[g] : negi[g - NPOS];
    const int b   = aidx / AHW;
    const int rem = aidx - b * AHW;
    const int a   = rem / HW_;
    const int hw  = rem - a * HW_;
    const int hh  = hw / W_;
    const int ww  = hw - hh * W_;

    const float2 h2 = *(const float2*)&H[(size_t)g * HID + 2 * lane];

    if (g < NPOS) {
        float out[25];
#pragma unroll
        for (int j = 0; j < 25; ++j) {
            const int row = (j < 5) ? (5 * a + j) : (40 + j);
            const float2 w = *(const float2*)&W2[(size_t)row * HID + 2 * lane];
            float v = fmaf(w.x, h2.x, w.y * h2.y);
#pragma unroll
            for (int off = 1; off < 64; off <<= 1) v += __shfl_xor(v, off, 64);
            out[j] = v + b2[row];
        }

        const float wa = anc[2 * a], ha = anc[2 * a + 1];
        const float cx = ww + 0.5f, cy = hh + 0.5f;
        const float ax1 = cx - 0.5f * wa, ay1 = cy - 0.5f * ha;
        const float ax2 = cx + 0.5f * wa, ay2 = cy + 0.5f * ha;
        const float areap = wa * ha;

        float v; int vi = lane;
        if (lane < 40) {
            const float* bb = &bboxes[(size_t)(b * 40 + lane) * 5];
            const float bx1 = bb[0], by1 = bb[1], bx2 = bb[2], by2 = bb[3];
            const float areab = (bx2 - bx1) * (by2 - by1);
            const float ix1 = fmaxf(ax1, bx1), iy1 = fmaxf(ay1, by1);
            const float ix2 = fminf(ax2, bx2), iy2 = fminf(ay2, by2);
            const float inter = fmaxf(ix2 - ix1, 0.0f) * fmaxf(iy2 - iy1, 0.0f);
            v = inter / (areap + areab - inter);
        } else {
            v = -1.0f;
        }
#pragma unroll
        for (int off = 1; off < 64; off <<= 1) {
            const float ov = __shfl_xor(v, off, 64);
            const int   oi = __shfl_xor(vi, off, 64);
            if (ov > v || (ov == v && oi < vi)) { v = ov; vi = oi; }
        }
        const int m = vi;

        const float* gt = &bboxes[(size_t)(b * 40 + m) * 5];
        const float gx1 = gt[0], gy1 = gt[1], gx2 = gt[2], gy2 = gt[3];
        const int   gcls = (int)gt[4];
        const float xb = 0.5f * (gx1 + gx2), yb = 0.5f * (gy1 + gy2);
        const float wb = gx2 - gx1, hb = gy2 - gy1;
        const float go0 = xb - cx, go1 = yb - cy;
        const float go2 = __logf(wb / wa), go3 = __logf(hb / ha);

        const float o0 = sigmoidf_(out[1]) - 0.5f;
        const float o1 = sigmoidf_(out[2]) - 0.5f;
        const float o2 = out[3], o3 = out[4];
        const float reg = (o0 - go0) * (o0 - go0) + (o1 - go1) * (o1 - go1) +
                          (o2 - go2) * (o2 - go2) + (o3 - go3) * (o3 - go3);

        const float conf = sigmoidf_(out[0]);
        const float conft = (conf - 1.0f) * (conf - 1.0f);

        float mx = out[5];
#pragma unroll
        for (int c = 1; c < 20; ++c) mx = fmaxf(mx, out[5 + c]);
        float se = 0.0f;
#pragma unroll
        for (int c = 0; c < 20; ++c) se += __expf(out[5 + c] - mx);
        float lgt = 0.0f;
#pragma unroll
        for (int c = 0; c < 20; ++c) if (c == gcls) lgt = out[5 + c];
        const float clst = -(lgt - mx - __logf(se));

        if (lane == 0)
            contrib[g] = conft * (1.0f / 4096.0f) + reg * (1.0f / 2048.0f) +
                         clst * (1.0f / 2048.0f);
    } else {
        const int row = 5 * a;
        const float2 w = *(const float2*)&W2[(size_t)row * HID + 2 * lane];
        float v = fmaf(w.x, h2.x, w.y * h2.y);
#pragma unroll
        for (int off = 1; off < 64; off <<= 1) v += __shfl_xor(v, off, 64);
        const float conf = sigmoidf_(v + b2[row]);
        if (lane == 0) contrib[g] = conf * conf * (1.0f / 4096.0f);
    }
}

// ---------------------------------------------------------------------------
// K4: final reduction
// ---------------------------------------------------------------------------
__global__ __launch_bounds__(256) void k_final(const float* __restrict__ contrib,
                                               float* __restrict__ out)
{
    __shared__ float red[256];
    const int t = threadIdx.x;
    float s = 0.0f;
    for (int i = t; i < NANCH; i += 256) s += contrib[i];
    red[t] = s;
    __syncthreads();
    for (int st = 128; st > 0; st >>= 1) {
        if (t < st) red[t] += red[t + st];
        __syncthreads();
    }
    if (t == 0) out[0] = red[0];
}

extern "C" void kernel_launch(void* const* d_in, const int* in_sizes, int n_in,
                              void* d_out, int out_size, void* d_ws, size_t ws_size,
                              hipStream_t stream)
{
    const float* F      = (const float*)d_in[0];
    const float* bboxes = (const float*)d_in[1];
    const int*   posi   = (const int*)d_in[2];
    const int*   negi   = (const int*)d_in[3];
    const float* W1     = (const float*)d_in[4];
    const float* b1     = (const float*)d_in[5];
    const float* W2     = (const float*)d_in[6];
    const float* b2     = (const float*)d_in[7];
    const float* anc    = (const float*)d_in[8];
    float* out = (float*)d_out;

    // workspace layout (bytes, each region 256B-aligned)
    char* ws = (char*)d_ws;
    const size_t off_cnt  = 0;                                  // 256 B
    const size_t off_list = 256;                                // 1 MB
    const size_t off_w1t  = off_list + (size_t)64 * CAP * 4;    // 640 KB
    const size_t off_G    = off_w1t + (size_t)CIN * HID * 4;    // 10 MB (bf16)
    const size_t off_Hp   = off_G + (size_t)NANCH * CIN * 2;    // KSEL MB (bf16)

    // pick K-split by workspace budget (chunk = 1280/KSEL, /16)
    int KSEL = 5;
    {
        const int opts[3] = {10, 8, 5};
        for (int i = 0; i < 3; ++i) {
            size_t need = off_Hp + (size_t)opts[i] * NANCH * HID * 2
                          + (size_t)NANCH * HID * 4 + NANCH * 4 + 256;
            if (need <= ws_size) { KSEL = opts[i]; break; }
        }
    }
    const size_t off_Hb = off_Hp + (size_t)KSEL * NANCH * HID * 2;
    const size_t off_ct = off_Hb + (size_t)NANCH * HID * 4;

    int*            cnt     = (int*)(ws + off_cnt);
    int*            list    = (int*)(ws + off_list);
    float*          W1T     = (float*)(ws + off_w1t);
    unsigned short* G       = (unsigned short*)(ws + off_G);
    unsigned short* Hp      = (unsigned short*)(ws + off_Hp);
    float*          Hbuf    = (float*)(ws + off_Hb);
    float*          contrib = (float*)(ws + off_ct);

    k_zero<<<1, 64, 0, stream>>>(cnt);
    k_bucket<<<NANCH / 256, 256, 0, stream>>>(posi, negi, cnt, list);
    k_transpose<<<(CIN * HID + 255) / 256, 256, 0, stream>>>(W1, W1T);
    k_gather<<<dim3(NGSLAB, 64), 256, 0, stream>>>(F, cnt, list, G);
    k_gemm2<<<dim3(64, KSEL), 256, 0, stream>>>(G, W1T, Hp, CIN / KSEL);
    k_reduce_bias<<<(NANCH * HID / 8) / 256, 256, 0, stream>>>(Hp, b1, Hbuf, KSEL);
    k_loss<<<NANCH / 4, 256, 0, stream>>>(Hbuf, W2, b2, posi, negi, bboxes, anc,
                                          contrib);
    k_final<<<1, 256, 0, stream>>>(contrib, out);
    (void)in_sizes; (void)n_in; (void)out_size;
}

// Round 4
// 108.955 us; speedup vs baseline: 1.8608x; 1.0576x over previous
//
#include <hip/hip_runtime.h>
#include <math.h>

#define NPOS   2048
#define NANCH  4096          // pos + neg
#define CIN    1280
#define HID    128
#define W_     28
#define HW_    784           // 28*28
#define AHW    7056          // 9*784
#define FB     (CIN*HW_)     // floats per batch image
#define CAP    4096          // per-image anchor list capacity
#define GSLAB  8             // channels per gather slab
#define NGSLAB (CIN/GSLAB)   // 160
#define NLINES 49            // 64B lines per channel plane (784*4/64)

__device__ __forceinline__ float sigmoidf_(float x) {
    return 1.0f / (1.0f + __expf(-x));
}
__device__ __forceinline__ unsigned short f2bf(float x) {   // RNE f32->bf16
    unsigned int u = __float_as_uint(x);
    return (unsigned short)((u + 0x7fffu + ((u >> 16) & 1u)) >> 16);
}
__device__ __forceinline__ float bf_lo(unsigned int w) { return __uint_as_float(w << 16); }
__device__ __forceinline__ float bf_hi(unsigned int w) { return __uint_as_float(w & 0xffff0000u); }

// ---------------------------------------------------------------------------
// K0: bucket anchors by image + build per-image 49-bit line masks.
// Slot order nondeterministic but all written values are slot-independent.
// pack = (g << 10) | hw
// ---------------------------------------------------------------------------
__global__ void k_bucket(const int* __restrict__ posi, const int* __restrict__ negi,
                         int* __restrict__ cnt, int* __restrict__ list,
                         unsigned* __restrict__ lmask) {
    const int g = blockIdx.x * 256 + threadIdx.x;
    if (g >= NANCH) return;
    const int aidx = (g < NPOS) ? posi[g] : negi[g - NPOS];
    const int b    = aidx / AHW;
    const int hw   = (aidx - b * AHW) % HW_;
    const int slot = atomicAdd(&cnt[b], 1);
    list[b * CAP + slot] = (g << 10) | hw;
    atomicOr(&lmask[2 * b + (hw >> 9)], 1u << ((hw >> 4) & 31));
}

// ---------------------------------------------------------------------------
// K1: line-compacted streaming gather (+ W1 transpose folded in).
// grid = (161, 64): blockIdx.x<160 -> gather slab, ==160 -> transpose chunk.
// Gather: stage only the used 64B lines of an 8-channel plane slab into a
// compacted LDS slab (coalesced float4, 16 lanes/line), then scatter this
// image's anchor columns to G[g][k] (bf16).
// ---------------------------------------------------------------------------
__global__ __launch_bounds__(256) void k_gather(
    const float* __restrict__ F, const float* __restrict__ W1,
    const int* __restrict__ cnt, const int* __restrict__ list,
    const unsigned* __restrict__ lmask, unsigned short* __restrict__ G,
    float* __restrict__ W1T)
{
    const int t = threadIdx.x;

    if (blockIdx.x == NGSLAB) {          // ---- transpose role: 64 blocks
        const int base = blockIdx.y * (CIN * HID / 64);
#pragma unroll
        for (int r = 0; r < (CIN * HID / 64) / 256; ++r) {
            const int id = base + r * 256 + t;
            const int o  = id / CIN;
            const int k  = id - o * CIN;
            W1T[(size_t)k * HID + o] = W1[id];
        }
        return;
    }

    __shared__ float Pl[GSLAB * NLINES * 16];   // 25088 B worst case
    __shared__ int   llist[NLINES];
    __shared__ int   lrank[NLINES];
    __shared__ int   nls;

    const int slab = blockIdx.x;
    const int b    = blockIdx.y;
    const int kb   = slab * GSLAB;

    if (t < 64) {
        const unsigned m0 = lmask[2 * b];
        const unsigned m1 = lmask[2 * b + 1];
        if (t < NLINES) {
            const unsigned m   = (t >> 5) ? m1 : m0;
            const int     used = (m >> (t & 31)) & 1;
            unsigned b0, b1v;
            if (t < 32) { b0 = m0 & ((1u << t) - 1u); b1v = 0u; }
            else        { b0 = m0; b1v = m1 & ((1u << (t - 32)) - 1u); }
            const int r = __popc(b0) + __popc(b1v);
            lrank[t] = r;
            if (used) llist[r] = t;
            if (t == 0) nls = __popc(m0) + __popc(m1);
        }
    }
    __syncthreads();

    const int nl  = nls;
    const int nf4 = nl * 4;       // float4 words per channel
    const int nw  = nl * 16;      // floats per channel

    // stage used lines, coalesced (16 lanes = one 64B line)
    {
        float4* P4 = (float4*)Pl;
        const float* fb = F + (size_t)b * FB + (size_t)kb * HW_;
        for (int i = t; i < GSLAB * nf4; i += 256) {
            const int c = i / nf4;
            const int r = i - c * nf4;
            const int l = r >> 2, q = r & 3;
            P4[i] = *(const float4*)&fb[c * HW_ + llist[l] * 16 + q * 4];
        }
    }
    __syncthreads();

    // scatter anchor columns
    const int nb = cnt[b];
    const int h  = t & 1;
    for (int s0 = 0; s0 < nb; s0 += 128) {
        const int idx = s0 + (t >> 1);
        if (idx < nb) {
            const int pk   = list[b * CAP + idx];
            const int hw   = pk & 1023;
            const int g    = pk >> 10;
            const int slot = lrank[hw >> 4] * 16 + (hw & 15);
            const float v0 = Pl[(4 * h + 0) * nw + slot];
            const float v1 = Pl[(4 * h + 1) * nw + slot];
            const float v2 = Pl[(4 * h + 2) * nw + slot];
            const float v3 = Pl[(4 * h + 3) * nw + slot];
            ushort4 o4;
            o4.x = f2bf(v0); o4.y = f2bf(v1); o4.z = f2bf(v2); o4.w = f2bf(v3);
            *(ushort4*)&G[(size_t)g * CIN + kb + 4 * h] = o4;
        }
    }
}

// ---------------------------------------------------------------------------
// K2: dense GEMM  Hp[ks][g][o] (bf16 partials) = G[g][kchunk] * W1T
// ---------------------------------------------------------------------------
__global__ __launch_bounds__(256) void k_gemm2(
    const unsigned short* __restrict__ G, const float* __restrict__ W1T,
    unsigned short* __restrict__ Hp, int kchunk)
{
    __shared__ float Gs[16][68];     // [kk][anchor]
    __shared__ float Wl[16][132];    // [kk][o]

    const int mt = blockIdx.x;
    const int ks = blockIdx.y;
    const int t  = threadIdx.x;
    const int g0 = mt * 64;
    const int kbase = ks * kchunk;
    const int tx = t & 15;           // 4 anchors each
    const int ty = t >> 4;           // 8 outputs each
    const int a  = t & 63;
    const int hh = (t >> 6) & 1;

    float acc[4][8];
#pragma unroll
    for (int i = 0; i < 4; ++i)
#pragma unroll
        for (int j = 0; j < 8; ++j) acc[i][j] = 0.0f;

    const int nsub = kchunk >> 4;
    for (int sub = 0; sub < nsub; ++sub) {
        const int kb = kbase + (sub << 4);
        __syncthreads();
        if (t < 128) {
            const uint4 raw = *(const uint4*)&G[(size_t)(g0 + a) * CIN + kb + 8 * hh];
            const int k8 = 8 * hh;
            Gs[k8 + 0][a] = bf_lo(raw.x); Gs[k8 + 1][a] = bf_hi(raw.x);
            Gs[k8 + 2][a] = bf_lo(raw.y); Gs[k8 + 3][a] = bf_hi(raw.y);
            Gs[k8 + 4][a] = bf_lo(raw.z); Gs[k8 + 5][a] = bf_hi(raw.z);
            Gs[k8 + 6][a] = bf_lo(raw.w); Gs[k8 + 7][a] = bf_hi(raw.w);
        }
#pragma unroll
        for (int r = 0; r < 2; ++r) {
            const int idx = t + 256 * r;
            const int kk  = idx >> 5;
            const int c4  = idx & 31;
            const float4 wv = *(const float4*)&W1T[(size_t)(kb + kk) * HID + 4 * c4];
            *(float4*)&Wl[kk][4 * c4] = wv;
        }
        __syncthreads();
#pragma unroll
        for (int kk = 0; kk < 16; ++kk) {
            const float4 g4 = *(const float4*)&Gs[kk][tx << 2];
            const float4 wA = *(const float4*)&Wl[kk][ty << 3];
            const float4 wB = *(const float4*)&Wl[kk][(ty << 3) + 4];
            const float gg[4] = {g4.x, g4.y, g4.z, g4.w};
            const float wv[8] = {wA.x, wA.y, wA.z, wA.w, wB.x, wB.y, wB.z, wB.w};
#pragma unroll
            for (int i = 0; i < 4; ++i)
#pragma unroll
                for (int j = 0; j < 8; ++j)
                    acc[i][j] = fmaf(gg[i], wv[j], acc[i][j]);
        }
    }

#pragma unroll
    for (int i = 0; i < 4; ++i) {
        uint4 pk;
        pk.x = (unsigned)f2bf(acc[i][0]) | ((unsigned)f2bf(acc[i][1]) << 16);
        pk.y = (unsigned)f2bf(acc[i][2]) | ((unsigned)f2bf(acc[i][3]) << 16);
        pk.z = (unsigned)f2bf(acc[i][4]) | ((unsigned)f2bf(acc[i][5]) << 16);
        pk.w = (unsigned)f2bf(acc[i][6]) | ((unsigned)f2bf(acc[i][7]) << 16);
        *(uint4*)&Hp[((size_t)ks * NANCH + g0 + (tx << 2) + i) * HID + (ty << 3)] = pk;
    }
}

// ---------------------------------------------------------------------------
// K3: wave-per-anchor. Sums KSEL bf16 partials + bias + leaky inline, then
// layer-2 rows + IoU/argmax + losses.
// ---------------------------------------------------------------------------
__global__ __launch_bounds__(256) void k_loss(
    const unsigned short* __restrict__ Hp, const float* __restrict__ b1,
    int ksel, const float* __restrict__ W2, const float* __restrict__ b2,
    const int* __restrict__ posi, const int* __restrict__ negi,
    const float* __restrict__ bboxes, const float* __restrict__ anc,
    float* __restrict__ contrib)
{
    const int wid  = threadIdx.x >> 6;
    const int lane = threadIdx.x & 63;
    const int g    = blockIdx.x * 4 + wid;

    const int aidx = (g < NPOS) ? posi[g] : negi[g - NPOS];
    const int b   = aidx / AHW;
    const int rem = aidx - b * AHW;
    const int a   = rem / HW_;
    const int hw  = rem - a * HW_;
    const int hh  = hw / W_;
    const int ww  = hw - hh * W_;

    // h values for this anchor: sum partials + bias + leaky (same order as before)
    float hx = b1[2 * lane], hy = b1[2 * lane + 1];
    for (int ks = 0; ks < ksel; ++ks) {
        const unsigned raw =
            *(const unsigned*)&Hp[((size_t)ks * NANCH + g) * HID + 2 * lane];
        hx += bf_lo(raw);
        hy += bf_hi(raw);
    }
    hx = (hx > 0.0f) ? hx : 0.01f * hx;
    hy = (hy > 0.0f) ? hy : 0.01f * hy;

    if (g < NPOS) {
        float out[25];
#pragma unroll
        for (int j = 0; j < 25; ++j) {
            const int row = (j < 5) ? (5 * a + j) : (40 + j);
            const float2 w = *(const float2*)&W2[(size_t)row * HID + 2 * lane];
            float v = fmaf(w.x, hx, w.y * hy);
#pragma unroll
            for (int off = 1; off < 64; off <<= 1) v += __shfl_xor(v, off, 64);
            out[j] = v + b2[row];
        }

        const float wa = anc[2 * a], ha = anc[2 * a + 1];
        const float cx = ww + 0.5f, cy = hh + 0.5f;
        const float ax1 = cx - 0.5f * wa, ay1 = cy - 0.5f * ha;
        const float ax2 = cx + 0.5f * wa, ay2 = cy + 0.5f * ha;
        const float areap = wa * ha;

        float v; int vi = lane;
        if (lane < 40) {
            const float* bb = &bboxes[(size_t)(b * 40 + lane) * 5];
            const float bx1 = bb[0], by1 = bb[1], bx2 = bb[2], by2 = bb[3];
            const float areab = (bx2 - bx1) * (by2 - by1);
            const float ix1 = fmaxf(ax1, bx1), iy1 = fmaxf(ay1, by1);
            const float ix2 = fminf(ax2, bx2), iy2 = fminf(ay2, by2);
            const float inter = fmaxf(ix2 - ix1, 0.0f) * fmaxf(iy2 - iy1, 0.0f);
            v = inter / (areap + areab - inter);
        } else {
            v = -1.0f;
        }
#pragma unroll
        for (int off = 1; off < 64; off <<= 1) {
            const float ov = __shfl_xor(v, off, 64);
            const int   oi = __shfl_xor(vi, off, 64);
            if (ov > v || (ov == v && oi < vi)) { v = ov; vi = oi; }
        }
        const int m = vi;

        const float* gt = &bboxes[(size_t)(b * 40 + m) * 5];
        const float gx1 = gt[0], gy1 = gt[1], gx2 = gt[2], gy2 = gt[3];
        const int   gcls = (int)gt[4];
        const float xb = 0.5f * (gx1 + gx2), yb = 0.5f * (gy1 + gy2);
        const float wb = gx2 - gx1, hb = gy2 - gy1;
        const float go0 = xb - cx, go1 = yb - cy;
        const float go2 = __logf(wb / wa), go3 = __logf(hb / ha);

        const float o0 = sigmoidf_(out[1]) - 0.5f;
        const float o1 = sigmoidf_(out[2]) - 0.5f;
        const float o2 = out[3], o3 = out[4];
        const float reg = (o0 - go0) * (o0 - go0) + (o1 - go1) * (o1 - go1) +
                          (o2 - go2) * (o2 - go2) + (o3 - go3) * (o3 - go3);

        const float conf = sigmoidf_(out[0]);
        const float conft = (conf - 1.0f) * (conf - 1.0f);

        float mx = out[5];
#pragma unroll
        for (int c = 1; c < 20; ++c) mx = fmaxf(mx, out[5 + c]);
        float se = 0.0f;
#pragma unroll
        for (int c = 0; c < 20; ++c) se += __expf(out[5 + c] - mx);
        float lgt = 0.0f;
#pragma unroll
        for (int c = 0; c < 20; ++c) if (c == gcls) lgt = out[5 + c];
        const float clst = -(lgt - mx - __logf(se));

        if (lane == 0)
            contrib[g] = conft * (1.0f / 4096.0f) + reg * (1.0f / 2048.0f) +
                         clst * (1.0f / 2048.0f);
    } else {
        const int row = 5 * a;
        const float2 w = *(const float2*)&W2[(size_t)row * HID + 2 * lane];
        float v = fmaf(w.x, hx, w.y * hy);
#pragma unroll
        for (int off = 1; off < 64; off <<= 1) v += __shfl_xor(v, off, 64);
        const float conf = sigmoidf_(v + b2[row]);
        if (lane == 0) contrib[g] = conf * conf * (1.0f / 4096.0f);
    }
}

// ---------------------------------------------------------------------------
// K4: final reduction
// ---------------------------------------------------------------------------
__global__ __launch_bounds__(256) void k_final(const float* __restrict__ contrib,
                                               float* __restrict__ out)
{
    __shared__ float red[256];
    const int t = threadIdx.x;
    float s = 0.0f;
    for (int i = t; i < NANCH; i += 256) s += contrib[i];
    red[t] = s;
    __syncthreads();
    for (int st = 128; st > 0; st >>= 1) {
        if (t < st) red[t] += red[t + st];
        __syncthreads();
    }
    if (t == 0) out[0] = red[0];
}

extern "C" void kernel_launch(void* const* d_in, const int* in_sizes, int n_in,
                              void* d_out, int out_size, void* d_ws, size_t ws_size,
                              hipStream_t stream)
{
    const float* F      = (const float*)d_in[0];
    const float* bboxes = (const float*)d_in[1];
    const int*   posi   = (const int*)d_in[2];
    const int*   negi   = (const int*)d_in[3];
    const float* W1     = (const float*)d_in[4];
    const float* b1     = (const float*)d_in[5];
    const float* W2     = (const float*)d_in[6];
    const float* b2     = (const float*)d_in[7];
    const float* anc    = (const float*)d_in[8];
    float* out = (float*)d_out;

    // workspace layout (bytes, 256B-aligned regions)
    char* ws = (char*)d_ws;
    const size_t off_cnt  = 0;                                  // 256 B
    const size_t off_lm   = 256;                                // 512 B
    const size_t off_list = 768;                                // 1 MB
    const size_t off_w1t  = off_list + (size_t)64 * CAP * 4;
    const size_t off_G    = off_w1t + (size_t)CIN * HID * 4;
    const size_t off_Hp   = off_G + (size_t)NANCH * CIN * 2;

    int KSEL = 5;
    {
        const int opts[3] = {10, 8, 5};
        for (int i = 0; i < 3; ++i) {
            size_t need = off_Hp + (size_t)opts[i] * NANCH * HID * 2 + NANCH * 4 + 256;
            if (need <= ws_size) { KSEL = opts[i]; break; }
        }
    }
    const size_t off_ct = off_Hp + (size_t)KSEL * NANCH * HID * 2;

    int*            cnt     = (int*)(ws + off_cnt);
    unsigned*       lmask   = (unsigned*)(ws + off_lm);
    int*            list    = (int*)(ws + off_list);
    float*          W1T     = (float*)(ws + off_w1t);
    unsigned short* G       = (unsigned short*)(ws + off_G);
    unsigned short* Hp      = (unsigned short*)(ws + off_Hp);
    float*          contrib = (float*)(ws + off_ct);

    hipMemsetAsync(ws, 0, 768, stream);   // cnt + lmask
    k_bucket<<<NANCH / 256, 256, 0, stream>>>(posi, negi, cnt, list, lmask);
    k_gather<<<dim3(NGSLAB + 1, 64), 256, 0, stream>>>(F, W1, cnt, list, lmask,
                                                       G, W1T);
    k_gemm2<<<dim3(64, KSEL), 256, 0, stream>>>(G, W1T, Hp, CIN / KSEL);
    k_loss<<<NANCH / 4, 256, 0, stream>>>(Hp, b1, KSEL, W2, b2, posi, negi,
                                          bboxes, anc, contrib);
    k_final<<<1, 256, 0, stream>>>(contrib, out);
    (void)in_sizes; (void)n_in; (void)out_size;
}